// Round 10
// baseline (232.980 us; speedup 1.0000x reference)
//
#include <hip/hip_runtime.h>
#include <math.h>

#define NB 8
#define NN 150
#define NE 299          // 2*N-1
#define NNODE (NB*NN)   // 1200
#define NG 4            // node-groups per block
#define GP 192          // threads per group
#define NBLK (NNODE/NG) // 300
#define STR 196

struct Quat { float w, x, y, z; };

__device__ inline Quat qmul(Quat a, Quat b) {
    Quat r;
    r.w = a.w*b.w - a.x*b.x - a.y*b.y - a.z*b.z;
    r.x = a.w*b.x + a.x*b.w + a.y*b.z - a.z*b.y;
    r.y = a.w*b.y - a.x*b.z + a.y*b.w + a.z*b.x;
    r.z = a.w*b.z + a.x*b.y - a.y*b.x + a.z*b.w;
    return r;
}
__device__ inline Quat qconj(Quat a) { return Quat{a.w, -a.x, -a.y, -a.z}; }

__device__ inline float3 qrot(Quat q, float3 v) {
    float tx = 2.f*(q.y*v.z - q.z*v.y);
    float ty = 2.f*(q.z*v.x - q.x*v.z);
    float tz = 2.f*(q.x*v.y - q.y*v.x);
    float cx = q.y*tz - q.z*ty;
    float cy = q.z*tx - q.x*tz;
    float cz = q.x*ty - q.y*tx;
    float3 r;
    r.x = v.x + q.w*tx + cx;
    r.y = v.y + q.w*ty + cy;
    r.z = v.z + q.w*tz + cz;
    return r;
}

// ---------------------------------------------------------------------------
// P1: layer 1 fully in-block; 4 independent node-groups per 768-thread block
// (grid 300). Per-group math identical to the proven round-9 pair1 block.
// Tail also produces ALL per-layer tables for layers 2..4 (weight-only).
// ---------------------------------------------------------------------------
struct Pair1Args {
    const float* quats; const float* trans; const float* feats; const int* tptr;
    const float* wm1; const float* bm1; const float* wq1; const float* bq1;
    const float* wf1; const float* bf1;
    const float* wmN; const float* bmN; const float* wqN; const float* bqN; // layer 2
    const float* wmT[3]; const float* wqT[3];   // layers 2,3,4 (tables)
    float* hout; float* Aout; float* Adout; float* Cout; float* Cdout;
    float* Pp; float* Edp; float* Gqp;          // table bases (regions 1..3)
    float* qout; float* xout;
};

__global__ __launch_bounds__(768, 6) void pair1_kernel(Pair1Args a)
{
    constexpr int GM = 16*STR;
    __shared__ __align__(16) float sMat[NG*GM];
    __shared__ float sPr[NG*64];
    __shared__ float sTot[NG*16];
    __shared__ float sHsum[NG*30], sEt[NG*32];
    __shared__ float sHi[NG*30], sA[NG*32], sCi[NG*32], sAd[NG*6];
    __shared__ float sWq[192], sWmCq[180], sGq[54];
    __shared__ float sMs[NG*32], sO[NG*64], sH2[NG*64], sA2[NG*32], sC2[NG*32];

    const int tid = threadIdx.x;
    const int g   = tid / GP;
    const int lt  = tid - g*GP;
    const int blk = blockIdx.x;
    const int gi  = blk*NG + g;          // this group's node
    const int b   = gi / NN;
    const int i   = gi - b*NN;
    const float tval = (float)a.tptr[0] * (1.0f/1000.0f);

    // ---- stage ----
    if (tid < 192) sWq[tid] = a.wq1[tid];
    if (tid >= 256 && tid < 376) {       // h_i (30 feats) x 4 groups
        const int t = tid - 256;
        const int gg = t / 30, d = t - gg*30;
        const int n = blk*NG + gg;
        float v;
        if      (d < 4)  v = a.quats[n*4 + d];
        else if (d < 7)  v = a.trans[n*3 + (d-4)];
        else if (d < 29) v = a.feats[n*22 + (d-7)];
        else             v = tval;
        sHi[gg*30 + d] = v;
    }
    __syncthreads();                                   // B0

    // WmCq = WmC@Wq, Gq = geomrows@Wq (shared); A_i/C_i per group
    if (tid < 180) {
        const int d = tid/6, dd = tid - d*6;
        float acc = 0.f;
#pragma unroll
        for (int k = 0; k < 32; ++k) acc = fmaf(a.wm1[(30+d)*32 + k], sWq[k*6+dd], acc);
        sWmCq[tid] = acc;
    }
    if (tid >= 192 && tid < 246) {
        const int t = tid - 192;
        const int tt = t/6, dd = t - tt*6;
        float acc = 0.f;
#pragma unroll
        for (int k = 0; k < 32; ++k) acc = fmaf(a.wm1[(60+NE+tt)*32 + k], sWq[k*6+dd], acc);
        sGq[t] = acc;
    }
    if (tid >= 256 && tid < 512) {
        const int t = tid - 256;
        const int gg = t >> 6, r = t & 63;
        const int k = r & 31, off = (r < 32) ? 0 : 30;
        float acc = (r < 32) ? a.bm1[k] : 0.f;
#pragma unroll
        for (int d = 0; d < 30; ++d) acc = fmaf(sHi[gg*30+d], a.wm1[(off+d)*32 + k], acc);
        if (r < 32) sA[gg*32+k] = acc; else sCi[gg*32+k] = acc;
    }
    __syncthreads();                                   // B1
    if (tid < 24) {                                    // Ad per group
        const int gg = tid/6, d = tid - gg*6;
        float acc = a.bq1[d];
#pragma unroll
        for (int k = 0; k < 32; ++k) acc = fmaf(sA[gg*32+k], sWq[k*6+d], acc);
        sAd[gg*6+d] = acc;
    }
    __syncthreads();                                   // B2

    // ---- strided partial sums (per group, registers, coalesced) ----
    float ep = 0.f;
    {
        const int ge = lt >> 5, ke = lt & 31;          // 6 groups x 32 channels
        const float* Eb = a.wm1 + (60 + i + ge*25)*32 + ke;
#pragma unroll 5
        for (int r = 0; r < 25; ++r) ep += Eb[r*32];
    }
    float hp = 0.f;
    if (lt < 180) {
        const int gh = lt/30, dh = lt - gh*30;
        const int jb = b*NN + gh*25;
        if (dh < 4)       { for (int r = 0; r < 25; ++r) hp += a.quats[(jb+r)*4 + dh]; }
        else if (dh < 7)  { for (int r = 0; r < 25; ++r) hp += a.trans[(jb+r)*3 + (dh-4)]; }
        else if (dh < 29) { for (int r = 0; r < 25; ++r) hp += a.feats[(jb+r)*22 + (dh-7)]; }
        else              hp = 25.f*tval;
    }

    const float4 qi4 = ((const float4*)a.quats)[gi];
    const Quat  qi = {qi4.x, qi4.y, qi4.z, qi4.w};
    const float3 xi = {sHi[g*30+4], sHi[g*30+5], sHi[g*30+6]};

    const bool act = (lt < NN);
    const int nodeJ = b*NN + lt;
    const float mm = (lt == i) ? 0.f : 1.f;

    float vals[16];
#pragma unroll
    for (int v = 0; v < 16; ++v) vals[v] = 0.f;

    if (act) {
        float hj[30];
        const float4 q4 = ((const float4*)a.quats)[nodeJ];
        hj[0]=q4.x; hj[1]=q4.y; hj[2]=q4.z; hj[3]=q4.w;
        hj[4]=a.trans[nodeJ*3+0]; hj[5]=a.trans[nodeJ*3+1]; hj[6]=a.trans[nodeJ*3+2];
#pragma unroll
        for (int d = 0; d < 22; ++d) hj[7+d] = a.feats[nodeJ*22 + d];
        hj[29] = tval;
        Quat qj = {hj[0], hj[1], hj[2], hj[3]};
        float3 xj = {hj[4], hj[5], hj[6]};

        // Cd_j = h_j @ WmCq
        float cd[6];
#pragma unroll
        for (int dd = 0; dd < 6; ++dd) cd[dd] = 0.f;
#pragma unroll
        for (int d = 0; d < 30; ++d) {
            const float hv = hj[d];
#pragma unroll
            for (int dd = 0; dd < 6; ++dd) cd[dd] = fmaf(hv, sWmCq[d*6+dd], cd[dd]);
        }

        float3 diff = {xi.x - xj.x, xi.y - xj.y, xi.z - xj.z};
        Quat qjc = qconj(qj);
        float3 lx = qrot(qjc, diff);
        Quat lq = qmul(qmul(qjc, qi), qj);
        const float d2v = diff.x*diff.x + diff.y*diff.y + diff.z*diff.z;
        const float dt = fabsf(qi.w*qj.w + qi.x*qj.x + qi.y*qj.y + qi.z*qj.z);
        const float gg9[9] = {lx.x, lx.y, lx.z, lq.w, lq.x, lq.y, lq.z, d2v, dt};

        float delta[6];
#pragma unroll
        for (int dd = 0; dd < 6; ++dd) delta[dd] = sAd[g*6+dd] + cd[dd];
        const float* Er = a.wm1 + (60 + (NN-1) + i - lt)*32;
#pragma unroll
        for (int k = 0; k < 32; ++k) {
            const float ev = Er[k];
#pragma unroll
            for (int dd = 0; dd < 6; ++dd) delta[dd] = fmaf(ev, sWq[k*6+dd], delta[dd]);
        }
#pragma unroll
        for (int t = 0; t < 9; ++t) {
            const float gv = gg9[t];
#pragma unroll
            for (int dd = 0; dd < 6; ++dd) delta[dd] = fmaf(gv, sGq[t*6+dd], delta[dd]);
        }
#pragma unroll
        for (int dd = 0; dd < 6; ++dd) delta[dd] *= mm;

#pragma unroll
        for (int t = 0; t < 9; ++t) vals[t] = gg9[t]*mm;
        float3 dv = {delta[3], delta[4], delta[5]};
        float3 rd = qrot(qj, dv);
        vals[9]  = rd.x; vals[10] = rd.y; vals[11] = rd.z;
        Quat vq = {0.f, delta[0], delta[1], delta[2]};
        Quat sp = qmul(lq, vq);
        vals[12] = lq.w + sp.w;
        vals[13] = lq.x + sp.x;
        vals[14] = lq.y + sp.y;
        vals[15] = lq.z + sp.z;
    }

    // ---- V-pass (per group) ----
    {
        float* gMat = sMat + g*GM;
#pragma unroll
        for (int v = 0; v < 16; ++v) gMat[v*STR + lt] = vals[v];
    }
    __syncthreads();                                   // B3
    if (tid < 256) {
        const int gg = tid >> 6, t = tid & 63;
        const int ch = t >> 2, q4i = t & 3;
        const float4* row = (const float4*)(sMat + gg*GM + ch*STR + q4i*48);
        float s0=0.f, s1=0.f, s2=0.f, s3=0.f;
#pragma unroll
        for (int it = 0; it < 12; ++it) {
            const float4 r = row[it];
            s0 += r.x; s1 += r.y; s2 += r.z; s3 += r.w;
        }
        sPr[gg*64 + t] = (s0+s1) + (s2+s3);
    }
    __syncthreads();                                   // B4
    if (tid < 64) {
        const int gg = tid >> 4, c = tid & 15;
        sTot[gg*16+c] = (sPr[gg*64+4*c] + sPr[gg*64+4*c+1])
                      + (sPr[gg*64+4*c+2] + sPr[gg*64+4*c+3]);
    }
    // scratch: dump strided partials into (now free) group sMat regions
    sMat[g*GM + lt] = ep;
    if (lt < 180) sMat[g*GM + 256 + lt] = hp;
    __syncthreads();                                   // B5

    // combine + epilogue
    if (tid < 128) {
        const int gg = tid >> 5, k = tid & 31;
        const float* s = sMat + gg*GM;
        sEt[gg*32+k] = ((s[k] + s[32+k]) + (s[64+k] + s[96+k])) + (s[128+k] + s[160+k]);
    } else if (tid >= 256 && tid < 376) {
        const int t = tid - 256;
        const int gg = t/30, d = t - gg*30;
        const float* s = sMat + gg*GM + 256;
        sHsum[gg*30+d] = ((s[d] + s[30+d]) + (s[60+d] + s[90+d])) + (s[120+d] + s[150+d]);
    } else if (tid >= 512 && tid < 516) {
        const int gg = tid - 512;
        const int n = blk*NG + gg;
        const float4 q4n = ((const float4*)a.quats)[n];
        const Quat qin = {q4n.x, q4n.y, q4n.z, q4n.w};
        const float inv = 1.0f / (float)(NN - 1);
        const float ux0 = ((float)NN * sHi[gg*30+4] + sTot[gg*16+9])  * inv;
        const float ux1 = ((float)NN * sHi[gg*30+5] + sTot[gg*16+10]) * inv;
        const float ux2 = ((float)NN * sHi[gg*30+6] + sTot[gg*16+11]) * inv;
        Quat s = {sTot[gg*16+12], sTot[gg*16+13], sTot[gg*16+14], sTot[gg*16+15]};
        const float nrm = sqrtf(s.w*s.w + s.x*s.x + s.y*s.y + s.z*s.z);
        const float invn = 1.0f / fmaxf(nrm, 1e-12f);
        Quat u = {s.w*invn, s.x*invn, s.y*invn, s.z*invn};
        Quat uq = qmul(qmul(qin, u), qconj(qin));
        a.qout[n*4+0] = uq.w; a.qout[n*4+1] = uq.x;
        a.qout[n*4+2] = uq.y; a.qout[n*4+3] = uq.z;
        a.xout[n*3+0] = ux0;  a.xout[n*3+1] = ux1;  a.xout[n*3+2] = ux2;
    }
    __syncthreads();                                   // B6

    // msum
    if (tid < 128) {
        const int gg = tid >> 5, k = tid & 31;
        float ms = 149.f*sA[gg*32+k] - sCi[gg*32+k] + sEt[gg*32+k]
                 - a.wm1[(60 + (NN-1))*32 + k];
#pragma unroll
        for (int d = 0; d < 30; ++d) ms = fmaf(sHsum[gg*30+d], a.wm1[(30+d)*32 + k], ms);
#pragma unroll
        for (int t = 0; t < 9; ++t) ms = fmaf(sTot[gg*16+t], a.wm1[(60+NE+t)*32 + k], ms);
        sMs[gg*32+k] = ms;
    }
    __syncthreads();                                   // B7

    // o = [h_i, msum] @ Wf1
    if (tid < 256) {
        const int gg = tid >> 6, c = tid & 63;
        float acc0 = a.bf1[c], acc1 = 0.f;
#pragma unroll
        for (int d = 0; d < 30; d += 2) {
            acc0 = fmaf(sHi[gg*30+d],   a.wf1[d*64 + c],     acc0);
            acc1 = fmaf(sHi[gg*30+d+1], a.wf1[(d+1)*64 + c], acc1);
        }
#pragma unroll
        for (int k = 0; k < 32; k += 2) {
            acc0 = fmaf(sMs[gg*32+k],   a.wf1[(30+k)*64 + c],   acc0);
            acc1 = fmaf(sMs[gg*32+k+1], a.wf1[(30+k+1)*64 + c], acc1);
        }
        sO[gg*64+c] = acc0 + acc1;
    }
    __syncthreads();                                   // B8

    // tail: L2 node work per group
    if (tid < 256) {
        const int gg = tid >> 6, c = tid & 63;
        const float hn = fmaxf(sO[gg*64+c], 0.f);
        sH2[gg*64+c] = hn;
        a.hout[(blk*NG+gg)*64 + c] = hn;
    }
    __syncthreads();                                   // B9
    if (tid < 256) {
        const int gg = tid >> 6, r = tid & 63;
        const int k = r & 31, off = (r < 32) ? 0 : 64;
        float acc = (r < 32) ? a.bmN[k] : 0.f;
#pragma unroll
        for (int d = 0; d < 64; ++d) acc = fmaf(sH2[gg*64+d], a.wmN[(off+d)*32 + k], acc);
        const int n = blk*NG + gg;
        if (r < 32) { sA2[gg*32+k] = acc; a.Aout[n*32+k] = acc; }
        else        { sC2[gg*32+k] = acc; a.Cout[n*32+k] = acc; }
    }
    __syncthreads();                                   // B10
    if (tid < 48) {
        const int gg = tid/12, rem = tid - gg*12;
        const int half = (rem >= 6) ? 1 : 0;
        const int d = rem - half*6;
        const float* src = half ? (sC2+gg*32) : (sA2+gg*32);
        float acc = half ? 0.f : a.bqN[d];
#pragma unroll
        for (int k = 0; k < 32; ++k) acc = fmaf(src[k], a.wqN[k*6 + d], acc);
        (half ? a.Cdout : a.Adout)[(blk*NG+gg)*8 + d] = acc;
    }

    // ---- tables for layers 2..4 (weight-only; spread over groups) ----
    if (gi < 3*NE && lt >= 64 && lt < 70) {            // Ed rows
        const int l = gi / NE, r = gi - l*NE;
        const float* EN = a.wmT[l] + 2*64*32;
        const float* Wq = a.wqT[l];
        const int dd = lt - 64;
        float acc = 0.f;
#pragma unroll
        for (int k = 0; k < 32; ++k) acc = fmaf(EN[r*32+k], Wq[k*6+dd], acc);
        a.Edp[(l+1)*2400 + r*8 + dd] = acc;
    }
    if (gi >= 900 && gi < 903 && lt >= 64 && lt < 118) {   // Gq
        const int l = gi - 900;
        const int t = lt - 64, tr = t/6, dd = t - tr*6;
        const float* EN = a.wmT[l] + 2*64*32;
        const float* Wq = a.wqT[l];
        float acc = 0.f;
#pragma unroll
        for (int k = 0; k < 32; ++k) acc = fmaf(EN[(NE+tr)*32+k], Wq[k*6+dd], acc);
        a.Gqp[(l+1)*64 + tr*6 + dd] = acc;
    }
    if (gi >= 910 && gi < 913 && lt < 32) {            // P prefix (serial, no barrier)
        const int l = gi - 910, k = lt;
        const float* EN = a.wmT[l] + 2*64*32;
        float* PL = a.Pp + (l+1)*9600;
        float run = 0.f;
#pragma unroll 4
        for (int r = 0; r < 300; ++r) {
            PL[r*32+k] = run;
            if (r < NE) run += EN[r*32+k];
        }
    }
}

// ---------------------------------------------------------------------------
// P2..P4: thin pair kernel, 4 groups per block (grid 300). Per-group math
// identical to round-9 thin block. No table code (pair1 made them all).
// ---------------------------------------------------------------------------
struct PairArgs {
    const float* qcur; const float* xcur;
    const float* hbuf; const float* Abuf; const float* Cin;
    const float* Adin; const float* Cdin;
    const float* Ed; const float* Gq; const float* P;
    const float* wm; const float* wf; const float* bf;
    const float* wmN; const float* bmN; const float* wqN; const float* bqN;
    float* hout; float* Aout; float* Adout; float* Cout; float* Cdout;
    float* qout; float* xout; float* dout;
};

template<bool COMPUTE_O, bool WRITE_OUT, bool TAIL_FULL>
__global__ __launch_bounds__(768, 6) void pair_kernel(PairArgs a)
{
    constexpr int HD  = 64;
    constexpr int NV  = COMPUTE_O ? 16 : 7;
    constexpr int GMv = NV*STR;
    __shared__ __align__(16) float sMat[NG*GMv];
    __shared__ float sPr[NG*64];
    __shared__ float sTot[NG*16];
    __shared__ float sHi[NG*64], sO[NG*64], sMs[NG*32];
    __shared__ float sGq[54], sAd[NG*6];
    __shared__ float sA2[NG*32], sC2[NG*32];

    const int tid = threadIdx.x;
    const int g   = tid / GP;
    const int lt  = tid - g*GP;
    const int blk = blockIdx.x;
    const int gi  = blk*NG + g;
    const int b   = gi / NN;
    const int i   = gi - b*NN;

    if (COMPUTE_O && tid < 256) {
        const int gg = tid >> 6, c = tid & 63;
        sHi[gg*64+c] = a.hbuf[(blk*NG+gg)*64 + c];
    }
    if (tid >= 256 && tid < 310) sGq[tid-256] = a.Gq[tid-256];
    if (tid >= 320 && tid < 344) {
        const int t = tid - 320;
        const int gg = t/6, d = t - gg*6;
        sAd[gg*6+d] = a.Adin[(blk*NG+gg)*8 + d];
    }
    __syncthreads();                                   // B0

    // strided C partial (per group; batch-wide sum shared via subtraction)
    float cp = 0.f;
    if (COMPUTE_O) {
        const int ge = lt >> 5, ke = lt & 31;
        const float* Cb = a.Cin + (b*NN + ge*25)*32 + ke;
#pragma unroll 5
        for (int r = 0; r < 25; ++r) cp += Cb[r*32];
    }

    const float4 qi4 = ((const float4*)a.qcur)[gi];
    const Quat  qi = {qi4.x, qi4.y, qi4.z, qi4.w};
    const float3 xi = {a.xcur[gi*3+0], a.xcur[gi*3+1], a.xcur[gi*3+2]};

    const bool act = (lt < NN);
    const int nodeJ = b*NN + lt;
    const float mm = (lt == i) ? 0.f : 1.f;

    float vals[NV];
#pragma unroll
    for (int v = 0; v < NV; ++v) vals[v] = 0.f;

    if (act) {
        const float4 q4 = ((const float4*)a.qcur)[nodeJ];
        Quat qj = {q4.x, q4.y, q4.z, q4.w};
        float3 xj = {a.xcur[nodeJ*3+0], a.xcur[nodeJ*3+1], a.xcur[nodeJ*3+2]};

        float3 diff = {xi.x - xj.x, xi.y - xj.y, xi.z - xj.z};
        Quat qjc = qconj(qj);
        float3 lx = qrot(qjc, diff);
        Quat lq = qmul(qmul(qjc, qi), qj);
        const float d2v = diff.x*diff.x + diff.y*diff.y + diff.z*diff.z;
        const float dt = fabsf(qi.w*qj.w + qi.x*qj.x + qi.y*qj.y + qi.z*qj.z);
        const float gg9[9] = {lx.x, lx.y, lx.z, lq.w, lq.x, lq.y, lq.z, d2v, dt};

        const float4* cd4 = (const float4*)(a.Cdin + nodeJ*8);
        const float4* ed4 = (const float4*)(a.Ed + (NN-1 + i - lt)*8);
        const float4 c0 = cd4[0], c1 = cd4[1];
        const float4 e0 = ed4[0], e1 = ed4[1];
        float delta[6];
        delta[0] = sAd[g*6+0] + c0.x + e0.x;
        delta[1] = sAd[g*6+1] + c0.y + e0.y;
        delta[2] = sAd[g*6+2] + c0.z + e0.z;
        delta[3] = sAd[g*6+3] + c0.w + e0.w;
        delta[4] = sAd[g*6+4] + c1.x + e1.x;
        delta[5] = sAd[g*6+5] + c1.y + e1.y;
#pragma unroll
        for (int t = 0; t < 9; ++t) {
            const float gv = gg9[t];
#pragma unroll
            for (int dd = 0; dd < 6; ++dd) delta[dd] = fmaf(gv, sGq[t*6 + dd], delta[dd]);
        }
#pragma unroll
        for (int dd = 0; dd < 6; ++dd) delta[dd] *= mm;

        constexpr int vo = COMPUTE_O ? 9 : 0;
        if (COMPUTE_O) {
#pragma unroll
            for (int t = 0; t < 9; ++t) vals[t] = gg9[t]*mm;
        }
        float3 dv = {delta[3], delta[4], delta[5]};
        float3 rd = qrot(qj, dv);
        vals[vo+0] = rd.x; vals[vo+1] = rd.y; vals[vo+2] = rd.z;
        Quat vq = {0.f, delta[0], delta[1], delta[2]};
        Quat sp = qmul(lq, vq);
        vals[vo+3] = lq.w + sp.w;
        vals[vo+4] = lq.x + sp.x;
        vals[vo+5] = lq.y + sp.y;
        vals[vo+6] = lq.z + sp.z;
    }

    // V-pass
    {
        float* gMat = sMat + g*GMv;
#pragma unroll
        for (int v = 0; v < NV; ++v) gMat[v*STR + lt] = vals[v];
    }
    __syncthreads();                                   // B1
    if (COMPUTE_O) {
        if (tid < 256) {
            const int gg = tid >> 6, t = tid & 63;
            const int ch = t >> 2, q4i = t & 3;
            const float4* row = (const float4*)(sMat + gg*GMv + ch*STR + q4i*48);
            float s0=0.f, s1=0.f, s2=0.f, s3=0.f;
#pragma unroll
            for (int it = 0; it < 12; ++it) {
                const float4 r = row[it];
                s0 += r.x; s1 += r.y; s2 += r.z; s3 += r.w;
            }
            sPr[gg*64 + t] = (s0+s1) + (s2+s3);
        }
    } else {
        if (tid < 128) {
            const int gg = tid >> 5, t = tid & 31;
            if (t < 28) {
                const int ch = t >> 2, q4i = t & 3;
                const float4* row = (const float4*)(sMat + gg*GMv + ch*STR + q4i*48);
                float s0=0.f, s1=0.f, s2=0.f, s3=0.f;
#pragma unroll
                for (int it = 0; it < 12; ++it) {
                    const float4 r = row[it];
                    s0 += r.x; s1 += r.y; s2 += r.z; s3 += r.w;
                }
                sPr[gg*64 + t] = (s0+s1) + (s2+s3);
            }
        }
    }
    __syncthreads();                                   // B2
    if (COMPUTE_O) {
        if (tid < 64) {
            const int gg = tid >> 4, c = tid & 15;
            sTot[gg*16+c] = (sPr[gg*64+4*c] + sPr[gg*64+4*c+1])
                          + (sPr[gg*64+4*c+2] + sPr[gg*64+4*c+3]);
        }
        sMat[g*GMv + lt] = cp;     // scratch
    } else {
        if (tid < 32) {
            const int gg = tid >> 3, c = tid & 7;
            if (c < 7)
                sTot[gg*16+c] = (sPr[gg*64+4*c] + sPr[gg*64+4*c+1])
                              + (sPr[gg*64+4*c+2] + sPr[gg*64+4*c+3]);
        }
    }
    __syncthreads();                                   // B3

    if (COMPUTE_O) {
        if (tid < 128) {
            const int gg = tid >> 5, k = tid & 31;
            const int n = blk*NG + gg;
            const int bN = n / NN, iN = n - bN*NN;
            (void)bN;
            const float* s = sMat + gg*GMv;
            const float csum = ((s[k] + s[32+k]) + (s[64+k] + s[96+k])) + (s[128+k] + s[160+k]);
            float ms = 149.f*a.Abuf[n*32 + k] + csum - a.Cin[n*32 + k]
                     + a.P[(iN+NN)*32 + k] - a.P[iN*32 + k]
                     - a.wm[(2*HD + (NN-1))*32 + k];
#pragma unroll
            for (int t = 0; t < 9; ++t)
                ms = fmaf(sTot[gg*16+t], a.wm[(2*HD + NE + t)*32 + k], ms);
            sMs[gg*32+k] = ms;
        } else if (tid >= 512 && tid < 516) {
            const int gg = tid - 512;
            const int n = blk*NG + gg;
            const float4 q4n = ((const float4*)a.qcur)[n];
            const Quat qin = {q4n.x, q4n.y, q4n.z, q4n.w};
            const float xin0 = a.xcur[n*3+0], xin1 = a.xcur[n*3+1], xin2 = a.xcur[n*3+2];
            const float inv = 1.0f / (float)(NN - 1);
            const float ux0 = ((float)NN * xin0 + sTot[gg*16+9])  * inv;
            const float ux1 = ((float)NN * xin1 + sTot[gg*16+10]) * inv;
            const float ux2 = ((float)NN * xin2 + sTot[gg*16+11]) * inv;
            Quat s = {sTot[gg*16+12], sTot[gg*16+13], sTot[gg*16+14], sTot[gg*16+15]};
            const float nrm = sqrtf(s.w*s.w + s.x*s.x + s.y*s.y + s.z*s.z);
            const float invn = 1.0f / fmaxf(nrm, 1e-12f);
            Quat u = {s.w*invn, s.x*invn, s.y*invn, s.z*invn};
            Quat uq = qmul(qmul(qin, u), qconj(qin));
            a.qout[n*4+0] = uq.w; a.qout[n*4+1] = uq.x;
            a.qout[n*4+2] = uq.y; a.qout[n*4+3] = uq.z;
            a.xout[n*3+0] = ux0;  a.xout[n*3+1] = ux1;  a.xout[n*3+2] = ux2;
        }
        __syncthreads();                               // B4

        if (tid < 256) {
            const int gg = tid >> 6, c = tid & 63;
            float acc0 = a.bf[c], acc1 = 0.f;
#pragma unroll 8
            for (int d = 0; d < HD; d += 2) {
                acc0 = fmaf(sHi[gg*64+d],   a.wf[d*64 + c],     acc0);
                acc1 = fmaf(sHi[gg*64+d+1], a.wf[(d+1)*64 + c], acc1);
            }
#pragma unroll 8
            for (int k = 0; k < 32; k += 2) {
                acc0 = fmaf(sMs[gg*32+k],   a.wf[(HD+k)*64 + c],   acc0);
                acc1 = fmaf(sMs[gg*32+k+1], a.wf[(HD+k+1)*64 + c], acc1);
            }
            sO[gg*64+c] = acc0 + acc1;
        }
        __syncthreads();                               // B5

        if (tid < 256) {
            const int gg = tid >> 6, c = tid & 63;
            const float hn = fmaxf(sO[gg*64+c], 0.f);
            sHi[gg*64+c] = hn;
            if (TAIL_FULL) a.hout[(blk*NG+gg)*64 + c] = hn;
        }
        __syncthreads();                               // B6
        if (tid < 256) {
            const int gg = tid >> 6, r = tid & 63;
            const int k = r & 31, off = (r < 32) ? 0 : 64;
            float acc = (r < 32) ? a.bmN[k] : 0.f;
#pragma unroll
            for (int d = 0; d < 64; ++d) acc = fmaf(sHi[gg*64+d], a.wmN[(off+d)*32 + k], acc);
            const int n = blk*NG + gg;
            if (r < 32) { sA2[gg*32+k] = acc; if (TAIL_FULL) a.Aout[n*32+k] = acc; }
            else        { sC2[gg*32+k] = acc; if (TAIL_FULL) a.Cout[n*32+k] = acc; }
        }
        __syncthreads();                               // B7
        if (tid < 48) {
            const int gg = tid/12, rem = tid - gg*12;
            const int half = (rem >= 6) ? 1 : 0;
            const int d = rem - half*6;
            const float* src = half ? (sC2+gg*32) : (sA2+gg*32);
            float acc = half ? 0.f : a.bqN[d];
#pragma unroll
            for (int k = 0; k < 32; ++k) acc = fmaf(src[k], a.wqN[k*6 + d], acc);
            (half ? a.Cdout : a.Adout)[(blk*NG+gg)*8 + d] = acc;
        }
    } else {
        if (tid < 4) {
            const int gg = tid;
            const int n = blk*NG + gg;
            const float4 q4n = ((const float4*)a.qcur)[n];
            const Quat qin = {q4n.x, q4n.y, q4n.z, q4n.w};
            const float xin0 = a.xcur[n*3+0], xin1 = a.xcur[n*3+1], xin2 = a.xcur[n*3+2];
            const float inv = 1.0f / (float)(NN - 1);
            const float ux0 = ((float)NN * xin0 + sTot[gg*16+0]) * inv;
            const float ux1 = ((float)NN * xin1 + sTot[gg*16+1]) * inv;
            const float ux2 = ((float)NN * xin2 + sTot[gg*16+2]) * inv;
            Quat s = {sTot[gg*16+3], sTot[gg*16+4], sTot[gg*16+5], sTot[gg*16+6]};
            const float nrm = sqrtf(s.w*s.w + s.x*s.x + s.y*s.y + s.z*s.z);
            const float invn = 1.0f / fmaxf(nrm, 1e-12f);
            Quat u = {s.w*invn, s.x*invn, s.y*invn, s.z*invn};
            Quat uq = qmul(qmul(qin, u), qconj(qin));
            if (WRITE_OUT) {
                float* op = a.dout + n*7;
                op[0] = uq.w; op[1] = uq.x; op[2] = uq.y; op[3] = uq.z;
                op[4] = ux0;  op[5] = ux1;  op[6] = ux2;
            } else {
                a.qout[n*4+0] = uq.w; a.qout[n*4+1] = uq.x;
                a.qout[n*4+2] = uq.y; a.qout[n*4+3] = uq.z;
                a.xout[n*3+0] = ux0;  a.xout[n*3+1] = ux1;  a.xout[n*3+2] = ux2;
            }
        }
    }
}

// ---------------------------------------------------------------------------

extern "C" void kernel_launch(void* const* d_in, const int* in_sizes, int n_in,
                              void* d_out, int out_size, void* d_ws, size_t ws_size,
                              hipStream_t stream) {
    const float* quats = (const float*)d_in[0];
    const float* trans = (const float*)d_in[1];
    const float* wm[4] = {(const float*)d_in[5],  (const float*)d_in[11],
                          (const float*)d_in[17], (const float*)d_in[23]};
    const float* bm[4] = {(const float*)d_in[6],  (const float*)d_in[12],
                          (const float*)d_in[18], (const float*)d_in[24]};
    const float* wf[4] = {(const float*)d_in[7],  (const float*)d_in[13],
                          (const float*)d_in[19], (const float*)d_in[25]};
    const float* bf[4] = {(const float*)d_in[8],  (const float*)d_in[14],
                          (const float*)d_in[20], (const float*)d_in[26]};
    const float* wq[4] = {(const float*)d_in[9],  (const float*)d_in[15],
                          (const float*)d_in[21], (const float*)d_in[27]};
    const float* bq[4] = {(const float*)d_in[10], (const float*)d_in[16],
                          (const float*)d_in[22], (const float*)d_in[28]};

    float* ws = (float*)d_ws;
    float* h   = ws;               // 1200*64
    float* A   = h   + NNODE*64;   // 1200*32
    float* CA  = A   + NNODE*32;   // 1200*32
    float* CB  = CA  + NNODE*32;   // 1200*32
    float* Ad  = CB  + NNODE*32;   // 1200*8
    float* CdA = Ad  + NNODE*8;    // 1200*8
    float* CdB = CdA + NNODE*8;    // 1200*8
    float* qA  = CdB + NNODE*8;    // 1200*4
    float* xA  = qA  + NNODE*4;    // 1200*3
    float* qB  = xA  + NNODE*3;    // 1200*4
    float* xB  = qB  + NNODE*4;    // 1200*3
    float* Pp  = xB  + NNODE*3;    // 4*300*32 (regions 1..3 used)
    float* Edp = Pp  + 4*9600;     // 4*300*8
    float* Gqp = Edp + 4*2400;     // 4*64

    // ---- P1: layer 1 fused; produces L2 node data + ALL tables ----
    Pair1Args p1;
    p1.quats = quats; p1.trans = trans;
    p1.feats = (const float*)d_in[2];
    p1.tptr  = (const int*)d_in[4];
    p1.wm1 = wm[0]; p1.bm1 = bm[0]; p1.wq1 = wq[0]; p1.bq1 = bq[0];
    p1.wf1 = wf[0]; p1.bf1 = bf[0];
    p1.wmN = wm[1]; p1.bmN = bm[1]; p1.wqN = wq[1]; p1.bqN = bq[1];
    for (int l = 0; l < 3; ++l) { p1.wmT[l] = wm[l+1]; p1.wqT[l] = wq[l+1]; }
    p1.hout = h; p1.Aout = A; p1.Adout = Ad; p1.Cout = CA; p1.Cdout = CdA;
    p1.Pp = Pp; p1.Edp = Edp; p1.Gqp = Gqp;
    p1.qout = qA; p1.xout = xA;
    pair1_kernel<<<dim3(NBLK), dim3(NG*GP), 0, stream>>>(p1);

    PairArgs p;
    p.dout = (float*)d_out;

    // ---- P2: layer 2 ----
    p.qcur = qA; p.xcur = xA;
    p.hbuf = h; p.Abuf = A; p.Cin = CA; p.Adin = Ad; p.Cdin = CdA;
    p.Ed = Edp + 1*2400; p.Gq = Gqp + 1*64; p.P = Pp + 1*9600;
    p.wm = wm[1]; p.wf = wf[1]; p.bf = bf[1];
    p.wmN = wm[2]; p.bmN = bm[2]; p.wqN = wq[2]; p.bqN = bq[2];
    p.hout = h; p.Aout = A; p.Adout = Ad; p.Cout = CB; p.Cdout = CdB;
    p.qout = qB; p.xout = xB;
    pair_kernel<true, false, true><<<dim3(NBLK), dim3(NG*GP), 0, stream>>>(p);

    // ---- P3: layer 3 (light tail: L4 needs only Ad/Cd) ----
    p.qcur = qB; p.xcur = xB;
    p.Cin = CB; p.Cdin = CdB;
    p.Ed = Edp + 2*2400; p.Gq = Gqp + 2*64; p.P = Pp + 2*9600;
    p.wm = wm[2]; p.wf = wf[2]; p.bf = bf[2];
    p.wmN = wm[3]; p.bmN = bm[3]; p.wqN = wq[3]; p.bqN = bq[3];
    p.Cout = CA; p.Cdout = CdA;
    p.qout = qA; p.xout = xA;
    pair_kernel<true, false, false><<<dim3(NBLK), dim3(NG*GP), 0, stream>>>(p);

    // ---- P4: layer 4 -> d_out ----
    p.qcur = qA; p.xcur = xA;
    p.Cin = CA; p.Cdin = CdA; p.Adin = Ad;
    p.Ed = Edp + 3*2400; p.Gq = Gqp + 3*64; p.P = Pp + 3*9600;
    p.wm = wm[3]; p.wf = wf[3]; p.bf = bf[3];
    p.wmN = wm[3]; p.bmN = bm[3]; p.wqN = wq[3]; p.bqN = bq[3];  // unused
    p.qout = nullptr; p.xout = nullptr;
    pair_kernel<false, true, false><<<dim3(NBLK), dim3(NG*GP), 0, stream>>>(p);
}

// Round 11
// 215.546 us; speedup vs baseline: 1.0809x; 1.0809x over previous
//
#include <hip/hip_runtime.h>
#include <math.h>

#define NB 8
#define NN 150
#define NE 299          // 2*N-1
#define NNODE (NB*NN)   // 1200

struct Quat { float w, x, y, z; };

__device__ inline Quat qmul(Quat a, Quat b) {
    Quat r;
    r.w = a.w*b.w - a.x*b.x - a.y*b.y - a.z*b.z;
    r.x = a.w*b.x + a.x*b.w + a.y*b.z - a.z*b.y;
    r.y = a.w*b.y - a.x*b.z + a.y*b.w + a.z*b.x;
    r.z = a.w*b.z + a.x*b.y - a.y*b.x + a.z*b.w;
    return r;
}
__device__ inline Quat qconj(Quat a) { return Quat{a.w, -a.x, -a.y, -a.z}; }

__device__ inline float3 qrot(Quat q, float3 v) {
    float tx = 2.f*(q.y*v.z - q.z*v.y);
    float ty = 2.f*(q.z*v.x - q.x*v.z);
    float tz = 2.f*(q.x*v.y - q.y*v.x);
    float cx = q.y*tz - q.z*ty;
    float cy = q.z*tx - q.x*tz;
    float cz = q.x*ty - q.y*tx;
    float3 r;
    r.x = v.x + q.w*tx + cx;
    r.y = v.y + q.w*ty + cy;
    r.z = v.z + q.w*tz + cz;
    return r;
}

// 16-row LDS-transpose reduce pass: after sMat rows are written, sum each
// channel over 192 cols into sPr[4*ch+quarter]. Caller totals + barrier.
__device__ __forceinline__ void reduce_pass(const float* sMat, float* sPr,
                                            int tid, int nch) {
    __syncthreads();
    if (tid < 4*nch) {
        const int ch = tid >> 2, q4i = tid & 3;
        const float4* row = (const float4*)(sMat + ch*196 + q4i*48);
        float s0=0.f, s1=0.f, s2=0.f, s3=0.f;
#pragma unroll
        for (int it = 0; it < 12; ++it) {
            const float4 r = row[it];
            s0 += r.x; s1 += r.y; s2 += r.z; s3 += r.w;
        }
        sPr[tid] = (s0+s1) + (s2+s3);
    }
    __syncthreads();
}

// ---------------------------------------------------------------------------
// P1: layer 1 fully in-block (no init dispatch).
//   Cd_j = h_j @ WmCq (WmCq = WmC@Wq staged, 30x6), Ed inline (192 FMA),
//   Hsum/Etot via LDS reduce passes; msum = 149A_i + (Hsum@WmC - C_i)
//   + (Etot - E149) + Gsum.WmG. Tail: L2 node work + L2 tables.
// ---------------------------------------------------------------------------
struct Pair1Args {
    const float* quats; const float* trans; const float* feats; const int* tptr;
    const float* wm1; const float* bm1; const float* wq1; const float* bq1;
    const float* wf1; const float* bf1;
    const float* wmN; const float* bmN; const float* wqN; const float* bqN;
    float* hout; float* Aout; float* Adout; float* Cout; float* Cdout;
    float* PN; float* EdN; float* GqN;
    float* qout; float* xout;
};

__global__ __launch_bounds__(192, 4) void pair1_kernel(Pair1Args a)
{
    constexpr int STR = 196;
    __shared__ __align__(16) float sMat[16*STR];
    __shared__ float sPr[64];
    __shared__ float sTot[16], sHsum[30], sEt[32];
    __shared__ float sHi[30], sA[32], sCi[32], sAd[6];
    __shared__ float sWq[192], sWmCq[180], sGq[54];
    __shared__ float sMs[32], sO[64], sH2[64], sA2[32], sC2[32];

    const int tid   = threadIdx.x;
    const int nodeI = blockIdx.x;
    const int b     = nodeI / NN;
    const int i     = nodeI - b*NN;
    const int j     = tid;
    const float tval = (float)a.tptr[0] * (1.0f/1000.0f);

    // stage raw
    sWq[tid] = a.wq1[tid];
    if (tid < 30) {
        float v;
        if      (tid < 4)  v = a.quats[nodeI*4 + tid];
        else if (tid < 7)  v = a.trans[nodeI*3 + (tid-4)];
        else if (tid < 29) v = a.feats[nodeI*22 + (tid-7)];
        else               v = tval;
        sHi[tid] = v;
    }
    __syncthreads();   // B0

    // WmCq = WmC@Wq (30x6), Gq = geomrows@Wq (9x6), A_i/C_i
    if (tid < 180) {
        const int d = tid/6, dd = tid - d*6;
        float acc = 0.f;
#pragma unroll
        for (int k = 0; k < 32; ++k) acc = fmaf(a.wm1[(30+d)*32 + k], sWq[k*6+dd], acc);
        sWmCq[tid] = acc;
    }
    if (tid < 54) {
        const int t = tid/6, dd = tid - t*6;
        float acc = 0.f;
#pragma unroll
        for (int k = 0; k < 32; ++k) acc = fmaf(a.wm1[(60+NE+t)*32 + k], sWq[k*6+dd], acc);
        sGq[tid] = acc;
    }
    if (tid >= 128) {
        const int t2 = tid - 128;
        const int k = t2 & 31;
        const int off = (t2 < 32) ? 0 : 30;
        float acc = (t2 < 32) ? a.bm1[k] : 0.f;
#pragma unroll
        for (int d = 0; d < 30; ++d) acc = fmaf(sHi[d], a.wm1[(off+d)*32 + k], acc);
        if (t2 < 32) sA[k] = acc; else sCi[k] = acc;
    }
    __syncthreads();   // B1
    if (tid < 6) {
        float acc = a.bq1[tid];
#pragma unroll
        for (int k = 0; k < 32; ++k) acc = fmaf(sA[k], sWq[k*6+tid], acc);
        sAd[tid] = acc;
    }
    __syncthreads();   // B2

    const float4 qi4 = ((const float4*)a.quats)[nodeI];
    const Quat  qi = {qi4.x, qi4.y, qi4.z, qi4.w};
    const float3 xi = {sHi[4], sHi[5], sHi[6]};

    const bool act = (j < NN);
    const int nodeJ = b*NN + j;
    const float mm = (j == i) ? 0.f : 1.f;

    float hj[30];
    float vals[16];
#pragma unroll
    for (int v = 0; v < 16; ++v) vals[v] = 0.f;

    if (act) {
        const float4 q4 = ((const float4*)a.quats)[nodeJ];
        hj[0]=q4.x; hj[1]=q4.y; hj[2]=q4.z; hj[3]=q4.w;
        hj[4]=a.trans[nodeJ*3+0]; hj[5]=a.trans[nodeJ*3+1]; hj[6]=a.trans[nodeJ*3+2];
#pragma unroll
        for (int d = 0; d < 22; ++d) hj[7+d] = a.feats[nodeJ*22 + d];
        hj[29] = tval;
        Quat qj = {hj[0], hj[1], hj[2], hj[3]};
        float3 xj = {hj[4], hj[5], hj[6]};

        // Cd_j = h_j @ WmCq
        float cd[6];
#pragma unroll
        for (int dd = 0; dd < 6; ++dd) cd[dd] = 0.f;
#pragma unroll
        for (int d = 0; d < 30; ++d) {
            const float hv = hj[d];
#pragma unroll
            for (int dd = 0; dd < 6; ++dd) cd[dd] = fmaf(hv, sWmCq[d*6+dd], cd[dd]);
        }

        // geometry
        float3 diff = {xi.x - xj.x, xi.y - xj.y, xi.z - xj.z};
        Quat qjc = qconj(qj);
        float3 lx = qrot(qjc, diff);
        Quat lq = qmul(qmul(qjc, qi), qj);
        const float d2v = diff.x*diff.x + diff.y*diff.y + diff.z*diff.z;
        const float dt = fabsf(qi.w*qj.w + qi.x*qj.x + qi.y*qj.y + qi.z*qj.z);
        const float g[9] = {lx.x, lx.y, lx.z, lq.w, lq.x, lq.y, lq.z, d2v, dt};

        // delta = Ad_i + Cd_j + (E row @ Wq) + g.Gq, then *mm
        float delta[6];
#pragma unroll
        for (int dd = 0; dd < 6; ++dd) delta[dd] = sAd[dd] + cd[dd];
        const float* Er = a.wm1 + (60 + (NN-1) + i - j)*32;
#pragma unroll
        for (int k = 0; k < 32; ++k) {
            const float ev = Er[k];
#pragma unroll
            for (int dd = 0; dd < 6; ++dd) delta[dd] = fmaf(ev, sWq[k*6+dd], delta[dd]);
        }
#pragma unroll
        for (int t = 0; t < 9; ++t) {
            const float gv = g[t];
#pragma unroll
            for (int dd = 0; dd < 6; ++dd) delta[dd] = fmaf(gv, sGq[t*6+dd], delta[dd]);
        }
#pragma unroll
        for (int dd = 0; dd < 6; ++dd) delta[dd] *= mm;

#pragma unroll
        for (int t = 0; t < 9; ++t) vals[t] = g[t]*mm;
        float3 dv = {delta[3], delta[4], delta[5]};
        float3 rd = qrot(qj, dv);
        vals[9]  = rd.x; vals[10] = rd.y; vals[11] = rd.z;
        Quat vq = {0.f, delta[0], delta[1], delta[2]};
        Quat sp = qmul(lq, vq);
        vals[12] = lq.w + sp.w;
        vals[13] = lq.x + sp.x;
        vals[14] = lq.y + sp.y;
        vals[15] = lq.z + sp.z;
    }

    // pass V: 16 vals channels
#pragma unroll
    for (int v = 0; v < 16; ++v) sMat[v*STR + tid] = vals[v];
    reduce_pass(sMat, sPr, tid, 16);
    if (tid < 16) sTot[tid] = (sPr[4*tid]+sPr[4*tid+1]) + (sPr[4*tid+2]+sPr[4*tid+3]);
    __syncthreads();

    // pass H1/H2: Hsum over full batch (incl. j==i, no mask)
#pragma unroll
    for (int r = 0; r < 16; ++r) sMat[r*STR + tid] = act ? hj[r] : 0.f;
    reduce_pass(sMat, sPr, tid, 16);
    if (tid < 16) sHsum[tid] = (sPr[4*tid]+sPr[4*tid+1]) + (sPr[4*tid+2]+sPr[4*tid+3]);
    __syncthreads();
#pragma unroll
    for (int r = 0; r < 14; ++r) sMat[r*STR + tid] = act ? hj[16+r] : 0.f;
    reduce_pass(sMat, sPr, tid, 14);
    if (tid < 14) sHsum[16+tid] = (sPr[4*tid]+sPr[4*tid+1]) + (sPr[4*tid+2]+sPr[4*tid+3]);
    __syncthreads();

    // pass E1/E2: Etot = sum over ALL j of E row (149+i-j) (reload, L2-hot)
    {
        const float* ErP = a.wm1 + (60 + (NN-1) + i - j)*32;
#pragma unroll
        for (int r = 0; r < 16; ++r) sMat[r*STR + tid] = act ? ErP[r] : 0.f;
        reduce_pass(sMat, sPr, tid, 16);
        if (tid < 16) sEt[tid] = (sPr[4*tid]+sPr[4*tid+1]) + (sPr[4*tid+2]+sPr[4*tid+3]);
        __syncthreads();
#pragma unroll
        for (int r = 0; r < 16; ++r) sMat[r*STR + tid] = act ? ErP[16+r] : 0.f;
        reduce_pass(sMat, sPr, tid, 16);
        if (tid < 16) sEt[16+tid] = (sPr[4*tid]+sPr[4*tid+1]) + (sPr[4*tid+2]+sPr[4*tid+3]);
        __syncthreads();
    }

    // msum + q/x epilogue
    if (tid < 32) {
        const int k = tid;
        float ms = 149.f*sA[k] - sCi[k] + sEt[k] - a.wm1[(60 + (NN-1))*32 + k];
#pragma unroll
        for (int d = 0; d < 30; ++d) ms = fmaf(sHsum[d], a.wm1[(30+d)*32 + k], ms);
#pragma unroll
        for (int t = 0; t < 9; ++t) ms = fmaf(sTot[t], a.wm1[(60+NE+t)*32 + k], ms);
        sMs[k] = ms;
    }
    if (tid == 64) {
        const float inv = 1.0f / (float)(NN - 1);
        const float ux0 = ((float)NN * xi.x + sTot[9])  * inv;
        const float ux1 = ((float)NN * xi.y + sTot[10]) * inv;
        const float ux2 = ((float)NN * xi.z + sTot[11]) * inv;
        Quat s = {sTot[12], sTot[13], sTot[14], sTot[15]};
        const float nrm = sqrtf(s.w*s.w + s.x*s.x + s.y*s.y + s.z*s.z);
        const float invn = 1.0f / fmaxf(nrm, 1e-12f);
        Quat u = {s.w*invn, s.x*invn, s.y*invn, s.z*invn};
        Quat uq = qmul(qmul(qi, u), qconj(qi));
        a.qout[nodeI*4+0] = uq.w; a.qout[nodeI*4+1] = uq.x;
        a.qout[nodeI*4+2] = uq.y; a.qout[nodeI*4+3] = uq.z;
        a.xout[nodeI*3+0] = ux0;  a.xout[nodeI*3+1] = ux1;
        a.xout[nodeI*3+2] = ux2;
    }
    __syncthreads();

    // o = [h_i, msum] @ Wf1
    if (tid < 64) {
        float acc0 = a.bf1[tid], acc1 = 0.f;
#pragma unroll
        for (int d = 0; d < 30; d += 2) {
            acc0 = fmaf(sHi[d],   a.wf1[d*64 + tid],     acc0);
            acc1 = fmaf(sHi[d+1], a.wf1[(d+1)*64 + tid], acc1);
        }
#pragma unroll
        for (int k = 0; k < 32; k += 2) {
            acc0 = fmaf(sMs[k],   a.wf1[(30+k)*64 + tid],   acc0);
            acc1 = fmaf(sMs[k+1], a.wf1[(30+k+1)*64 + tid], acc1);
        }
        sO[tid] = acc0 + acc1;
    }
    __syncthreads();

    // tail: L2 node work
    if (tid < 64) {
        const float hn = fmaxf(sO[tid], 0.f);
        sH2[tid] = hn;
        a.hout[nodeI*64 + tid] = hn;
    }
    __syncthreads();
    if (tid < 64) {
        const int k   = tid & 31;
        const int off = (tid >= 32) ? 64 : 0;
        float acc = (tid < 32) ? a.bmN[k] : 0.f;
#pragma unroll
        for (int d = 0; d < 64; ++d) acc = fmaf(sH2[d], a.wmN[(off+d)*32 + k], acc);
        if (tid < 32) { sA2[k] = acc; a.Aout[nodeI*32 + k] = acc; }
        else          { sC2[k] = acc; a.Cout[nodeI*32 + k] = acc; }
    }
    __syncthreads();
    if (tid < 12) {
        const int half = (tid >= 6) ? 1 : 0;
        const int dd = tid - half*6;
        const float* src = half ? sC2 : sA2;
        float acc = half ? 0.f : a.bqN[dd];
#pragma unroll
        for (int k = 0; k < 32; ++k) acc = fmaf(src[k], a.wqN[k*6 + dd], acc);
        (half ? a.Cdout : a.Adout)[nodeI*8 + dd] = acc;
    }

    // L2 tables
    const float* EN = a.wmN + 2*64*32;
    if (nodeI < NE && tid >= 64 && tid < 70) {
        const int dd = tid - 64;
        float acc = 0.f;
#pragma unroll
        for (int k = 0; k < 32; ++k) acc = fmaf(EN[nodeI*32+k], a.wqN[k*6+dd], acc);
        a.EdN[nodeI*8+dd] = acc;
    }
    if (nodeI == 1100 && tid >= 64 && tid < 118) {
        const int tt = tid-64; const int tr = tt/6, dd = tt - tr*6;
        float acc = 0.f;
#pragma unroll
        for (int k = 0; k < 32; ++k) acc = fmaf(EN[(NE+tr)*32+k], a.wqN[k*6+dd], acc);
        a.GqN[tr*6+dd] = acc;
    }
    if (nodeI == 1101) {
        __syncthreads();
        const int gp = tid >> 5, k = tid & 31;   // 6 groups x 32 channels
        const int r0 = gp*50;
        float part = 0.f;
        for (int r = r0; r < r0+50 && r < NE; ++r) part += EN[r*32 + k];
        sMat[gp*32 + k] = part;
        __syncthreads();
        float run = 0.f;
        for (int gg = 0; gg < gp; ++gg) run += sMat[gg*32 + k];
        for (int r = r0; r < r0+50; ++r) {
            a.PN[r*32 + k] = run;
            if (r < NE) run += EN[r*32 + k];
        }
    }
}

// ---------------------------------------------------------------------------
// P2..P4: thin pair kernel. One V-pass; ΣC via strided coalesced global sum
// (no atomics, no memset); tables for next layer in tail (COMPUTE_O).
// ---------------------------------------------------------------------------
struct PairArgs {
    const float* qcur; const float* xcur;
    const float* hbuf; const float* Abuf; const float* Cin;
    const float* Adin; const float* Cdin;
    const float* Ed; const float* Gq; const float* P;
    const float* wm; const float* wf; const float* bf;
    const float* wmN; const float* bmN; const float* wqN; const float* bqN;
    float* hout; float* Aout; float* Adout; float* Cout; float* Cdout;
    float* PN; float* EdN; float* GqN;
    float* qout; float* xout; float* dout;
};

template<bool COMPUTE_O, bool WRITE_OUT, bool TAIL_FULL>
__global__ __launch_bounds__(192, 4) void pair_kernel(PairArgs a)
{
    constexpr int HD  = 64;
    constexpr int STR = 196;
    constexpr int NV  = COMPUTE_O ? 16 : 7;
    __shared__ __align__(16) float sMat[NV*STR];
    __shared__ float sPr[64];
    __shared__ float sTot[16];
    __shared__ float sHi[64], sO[64], sMs[32];
    __shared__ float sGq[54], sAd[6];
    __shared__ float sA2[32], sC2[32];

    const int tid   = threadIdx.x;
    const int nodeI = blockIdx.x;
    const int b     = nodeI / NN;
    const int i     = nodeI - b*NN;
    const int j     = tid;

    if (COMPUTE_O) { if (tid < HD) sHi[tid] = a.hbuf[nodeI*64 + tid]; }
    if (tid < 54) sGq[tid] = a.Gq[tid];
    if (tid >= 64 && tid < 70) sAd[tid-64] = a.Adin[nodeI*8 + (tid-64)];
    __syncthreads();   // B0

    // strided C partial (coalesced, L2-hot)
    float cp = 0.f;
    if (COMPUTE_O) {
        const int gc = tid >> 5, kc = tid & 31;
        const float* Cb = a.Cin + (b*NN + gc*25)*32 + kc;
#pragma unroll 5
        for (int r = 0; r < 25; ++r) cp += Cb[r*32];
    }

    const float4 qi4 = ((const float4*)a.qcur)[nodeI];
    const Quat  qi = {qi4.x, qi4.y, qi4.z, qi4.w};
    const float3 xi = {a.xcur[nodeI*3+0], a.xcur[nodeI*3+1], a.xcur[nodeI*3+2]};

    const bool act = (j < NN);
    const int nodeJ = b*NN + j;
    const float mm = (j == i) ? 0.f : 1.f;

    float vals[NV];
#pragma unroll
    for (int v = 0; v < NV; ++v) vals[v] = 0.f;

    if (act) {
        const float4 q4 = ((const float4*)a.qcur)[nodeJ];
        Quat qj = {q4.x, q4.y, q4.z, q4.w};
        float3 xj = {a.xcur[nodeJ*3+0], a.xcur[nodeJ*3+1], a.xcur[nodeJ*3+2]};

        float3 diff = {xi.x - xj.x, xi.y - xj.y, xi.z - xj.z};
        Quat qjc = qconj(qj);
        float3 lx = qrot(qjc, diff);
        Quat lq = qmul(qmul(qjc, qi), qj);
        const float d2v = diff.x*diff.x + diff.y*diff.y + diff.z*diff.z;
        const float dt = fabsf(qi.w*qj.w + qi.x*qj.x + qi.y*qj.y + qi.z*qj.z);
        const float g[9] = {lx.x, lx.y, lx.z, lq.w, lq.x, lq.y, lq.z, d2v, dt};

        const float4* cd4 = (const float4*)(a.Cdin + nodeJ*8);
        const float4* ed4 = (const float4*)(a.Ed + (NN-1 + i - j)*8);
        const float4 c0 = cd4[0], c1 = cd4[1];
        const float4 e0 = ed4[0], e1 = ed4[1];
        float delta[6];
        delta[0] = sAd[0] + c0.x + e0.x;
        delta[1] = sAd[1] + c0.y + e0.y;
        delta[2] = sAd[2] + c0.z + e0.z;
        delta[3] = sAd[3] + c0.w + e0.w;
        delta[4] = sAd[4] + c1.x + e1.x;
        delta[5] = sAd[5] + c1.y + e1.y;
#pragma unroll
        for (int t = 0; t < 9; ++t) {
            const float gv = g[t];
#pragma unroll
            for (int dd = 0; dd < 6; ++dd) delta[dd] = fmaf(gv, sGq[t*6 + dd], delta[dd]);
        }
#pragma unroll
        for (int dd = 0; dd < 6; ++dd) delta[dd] *= mm;

        constexpr int vo = COMPUTE_O ? 9 : 0;
        if (COMPUTE_O) {
#pragma unroll
            for (int t = 0; t < 9; ++t) vals[t] = g[t]*mm;
        }
        float3 dv = {delta[3], delta[4], delta[5]};
        float3 rd = qrot(qj, dv);
        vals[vo+0] = rd.x; vals[vo+1] = rd.y; vals[vo+2] = rd.z;
        Quat vq = {0.f, delta[0], delta[1], delta[2]};
        Quat sp = qmul(lq, vq);
        vals[vo+3] = lq.w + sp.w;
        vals[vo+4] = lq.x + sp.x;
        vals[vo+5] = lq.y + sp.y;
        vals[vo+6] = lq.z + sp.z;
    }

    // V-pass (the only LDS reduce pass)
#pragma unroll
    for (int v = 0; v < NV; ++v) sMat[v*STR + tid] = vals[v];
    reduce_pass(sMat, sPr, tid, NV);
    if (tid < NV) sTot[tid] = (sPr[4*tid]+sPr[4*tid+1]) + (sPr[4*tid+2]+sPr[4*tid+3]);
    __syncthreads();

    if (COMPUTE_O) {
        // combine C partials via sMat scratch
        sMat[tid] = cp;
        __syncthreads();
        if (tid < 32) {
            const int k = tid;
            const float csum = ((sMat[k] + sMat[32+k]) + (sMat[64+k] + sMat[96+k]))
                             + (sMat[128+k] + sMat[160+k]);
            float ms = 149.f*a.Abuf[nodeI*32 + k] + csum - a.Cin[nodeI*32 + k]
                     + a.P[(i+NN)*32 + k] - a.P[i*32 + k]
                     - a.wm[(2*HD + (NN-1))*32 + k];
#pragma unroll
            for (int t = 0; t < 9; ++t)
                ms = fmaf(sTot[t], a.wm[(2*HD + NE + t)*32 + k], ms);
            sMs[k] = ms;
        }
        if (tid == 64) {
            const float inv = 1.0f / (float)(NN - 1);
            const float ux0 = ((float)NN * xi.x + sTot[9])  * inv;
            const float ux1 = ((float)NN * xi.y + sTot[10]) * inv;
            const float ux2 = ((float)NN * xi.z + sTot[11]) * inv;
            Quat s = {sTot[12], sTot[13], sTot[14], sTot[15]};
            const float nrm = sqrtf(s.w*s.w + s.x*s.x + s.y*s.y + s.z*s.z);
            const float invn = 1.0f / fmaxf(nrm, 1e-12f);
            Quat u = {s.w*invn, s.x*invn, s.y*invn, s.z*invn};
            Quat uq = qmul(qmul(qi, u), qconj(qi));
            a.qout[nodeI*4+0] = uq.w; a.qout[nodeI*4+1] = uq.x;
            a.qout[nodeI*4+2] = uq.y; a.qout[nodeI*4+3] = uq.z;
            a.xout[nodeI*3+0] = ux0;  a.xout[nodeI*3+1] = ux1;
            a.xout[nodeI*3+2] = ux2;
        }
        __syncthreads();

        if (tid < 64) {
            float acc0 = a.bf[tid], acc1 = 0.f;
#pragma unroll 8
            for (int d = 0; d < HD; d += 2) {
                acc0 = fmaf(sHi[d],   a.wf[d*64 + tid],     acc0);
                acc1 = fmaf(sHi[d+1], a.wf[(d+1)*64 + tid], acc1);
            }
#pragma unroll 8
            for (int k = 0; k < 32; k += 2) {
                acc0 = fmaf(sMs[k],   a.wf[(HD+k)*64 + tid],   acc0);
                acc1 = fmaf(sMs[k+1], a.wf[(HD+k+1)*64 + tid], acc1);
            }
            sO[tid] = acc0 + acc1;
        }
        __syncthreads();

        // tail: next layer node work
        if (tid < 64) {
            const float hn = fmaxf(sO[tid], 0.f);
            sHi[tid] = hn;
            if (TAIL_FULL) a.hout[nodeI*64 + tid] = hn;
        }
        __syncthreads();
        if (tid < 64) {
            const int k   = tid & 31;
            const int off = (tid >= 32) ? 64 : 0;
            float acc = (tid < 32) ? a.bmN[k] : 0.f;
#pragma unroll
            for (int d = 0; d < 64; ++d) acc = fmaf(sHi[d], a.wmN[(off+d)*32 + k], acc);
            if (tid < 32) { sA2[k] = acc; if (TAIL_FULL) a.Aout[nodeI*32 + k] = acc; }
            else          { sC2[k] = acc; if (TAIL_FULL) a.Cout[nodeI*32 + k] = acc; }
        }
        __syncthreads();
        if (tid < 12) {
            const int half = (tid >= 6) ? 1 : 0;
            const int dd = tid - half*6;
            const float* src = half ? sC2 : sA2;
            float acc = half ? 0.f : a.bqN[dd];
#pragma unroll
            for (int k = 0; k < 32; ++k) acc = fmaf(src[k], a.wqN[k*6 + dd], acc);
            (half ? a.Cdout : a.Adout)[nodeI*8 + dd] = acc;
        }

        // next-layer tables
        const float* EN = a.wmN + 2*64*32;
        if (nodeI < NE && tid >= 64 && tid < 70) {
            const int dd = tid - 64;
            float acc = 0.f;
#pragma unroll
            for (int k = 0; k < 32; ++k) acc = fmaf(EN[nodeI*32+k], a.wqN[k*6+dd], acc);
            a.EdN[nodeI*8+dd] = acc;
        }
        if (nodeI == 1100 && tid >= 64 && tid < 118) {
            const int tt = tid-64; const int tr = tt/6, dd = tt - tr*6;
            float acc = 0.f;
#pragma unroll
            for (int k = 0; k < 32; ++k) acc = fmaf(EN[(NE+tr)*32+k], a.wqN[k*6+dd], acc);
            a.GqN[tr*6+dd] = acc;
        }
        if (nodeI == 1101) {
            __syncthreads();
            const int gp = tid >> 5, k = tid & 31;
            const int r0 = gp*50;
            float part = 0.f;
            for (int r = r0; r < r0+50 && r < NE; ++r) part += EN[r*32 + k];
            sMat[gp*32 + k] = part;
            __syncthreads();
            float run = 0.f;
            for (int gg = 0; gg < gp; ++gg) run += sMat[gg*32 + k];
            for (int r = r0; r < r0+50; ++r) {
                a.PN[r*32 + k] = run;
                if (r < NE) run += EN[r*32 + k];
            }
        }
    } else {
        if (tid == 0) {
            const float inv = 1.0f / (float)(NN - 1);
            const float ux0 = ((float)NN * xi.x + sTot[0]) * inv;
            const float ux1 = ((float)NN * xi.y + sTot[1]) * inv;
            const float ux2 = ((float)NN * xi.z + sTot[2]) * inv;
            Quat s = {sTot[3], sTot[4], sTot[5], sTot[6]};
            const float nrm = sqrtf(s.w*s.w + s.x*s.x + s.y*s.y + s.z*s.z);
            const float invn = 1.0f / fmaxf(nrm, 1e-12f);
            Quat u = {s.w*invn, s.x*invn, s.y*invn, s.z*invn};
            Quat uq = qmul(qmul(qi, u), qconj(qi));
            if (WRITE_OUT) {
                float* op = a.dout + nodeI*7;
                op[0] = uq.w; op[1] = uq.x; op[2] = uq.y; op[3] = uq.z;
                op[4] = ux0;  op[5] = ux1;  op[6] = ux2;
            } else {
                a.qout[nodeI*4+0] = uq.w; a.qout[nodeI*4+1] = uq.x;
                a.qout[nodeI*4+2] = uq.y; a.qout[nodeI*4+3] = uq.z;
                a.xout[nodeI*3+0] = ux0;  a.xout[nodeI*3+1] = ux1;
                a.xout[nodeI*3+2] = ux2;
            }
        }
    }
}

// ---------------------------------------------------------------------------

extern "C" void kernel_launch(void* const* d_in, const int* in_sizes, int n_in,
                              void* d_out, int out_size, void* d_ws, size_t ws_size,
                              hipStream_t stream) {
    const float* quats = (const float*)d_in[0];
    const float* trans = (const float*)d_in[1];
    const float* wm[4] = {(const float*)d_in[5],  (const float*)d_in[11],
                          (const float*)d_in[17], (const float*)d_in[23]};
    const float* bm[4] = {(const float*)d_in[6],  (const float*)d_in[12],
                          (const float*)d_in[18], (const float*)d_in[24]};
    const float* wf[4] = {(const float*)d_in[7],  (const float*)d_in[13],
                          (const float*)d_in[19], (const float*)d_in[25]};
    const float* bf[4] = {(const float*)d_in[8],  (const float*)d_in[14],
                          (const float*)d_in[20], (const float*)d_in[26]};
    const float* wq[4] = {(const float*)d_in[9],  (const float*)d_in[15],
                          (const float*)d_in[21], (const float*)d_in[27]};
    const float* bq[4] = {(const float*)d_in[10], (const float*)d_in[16],
                          (const float*)d_in[22], (const float*)d_in[28]};

    float* ws = (float*)d_ws;
    float* h   = ws;               // 1200*64
    float* A   = h   + NNODE*64;   // 1200*32
    float* CA  = A   + NNODE*32;   // 1200*32
    float* CB  = CA  + NNODE*32;   // 1200*32
    float* Ad  = CB  + NNODE*32;   // 1200*8
    float* CdA = Ad  + NNODE*8;    // 1200*8
    float* CdB = CdA + NNODE*8;    // 1200*8
    float* qA  = CdB + NNODE*8;    // 1200*4
    float* xA  = qA  + NNODE*4;    // 1200*3
    float* qB  = xA  + NNODE*3;    // 1200*4
    float* xB  = qB  + NNODE*4;    // 1200*3
    float* Pp  = xB  + NNODE*3;    // 4*300*32 (regions 1..3 used)
    float* Edp = Pp  + 4*9600;     // 4*300*8
    float* Gqp = Edp + 4*2400;     // 4*64

    // ---- P1: layer 1 fused; produces L2 node data + tables ----
    Pair1Args p1;
    p1.quats = quats; p1.trans = trans;
    p1.feats = (const float*)d_in[2];
    p1.tptr  = (const int*)d_in[4];
    p1.wm1 = wm[0]; p1.bm1 = bm[0]; p1.wq1 = wq[0]; p1.bq1 = bq[0];
    p1.wf1 = wf[0]; p1.bf1 = bf[0];
    p1.wmN = wm[1]; p1.bmN = bm[1]; p1.wqN = wq[1]; p1.bqN = bq[1];
    p1.hout = h; p1.Aout = A; p1.Adout = Ad; p1.Cout = CA; p1.Cdout = CdA;
    p1.PN = Pp + 1*9600; p1.EdN = Edp + 1*2400; p1.GqN = Gqp + 1*64;
    p1.qout = qA; p1.xout = xA;
    pair1_kernel<<<dim3(NNODE), dim3(192), 0, stream>>>(p1);

    PairArgs p;
    p.dout = (float*)d_out;

    // ---- P2: layer 2 ----
    p.qcur = qA; p.xcur = xA;
    p.hbuf = h; p.Abuf = A; p.Cin = CA; p.Adin = Ad; p.Cdin = CdA;
    p.Ed = Edp + 1*2400; p.Gq = Gqp + 1*64; p.P = Pp + 1*9600;
    p.wm = wm[1]; p.wf = wf[1]; p.bf = bf[1];
    p.wmN = wm[2]; p.bmN = bm[2]; p.wqN = wq[2]; p.bqN = bq[2];
    p.hout = h; p.Aout = A; p.Adout = Ad; p.Cout = CB; p.Cdout = CdB;
    p.PN = Pp + 2*9600; p.EdN = Edp + 2*2400; p.GqN = Gqp + 2*64;
    p.qout = qB; p.xout = xB;
    pair_kernel<true, false, true><<<dim3(NNODE), dim3(192), 0, stream>>>(p);

    // ---- P3: layer 3 (light tail: L4 needs only Ad/Cd + tables) ----
    p.qcur = qB; p.xcur = xB;
    p.Cin = CB; p.Cdin = CdB;
    p.Ed = Edp + 2*2400; p.Gq = Gqp + 2*64; p.P = Pp + 2*9600;
    p.wm = wm[2]; p.wf = wf[2]; p.bf = bf[2];
    p.wmN = wm[3]; p.bmN = bm[3]; p.wqN = wq[3]; p.bqN = bq[3];
    p.Cout = CA; p.Cdout = CdA;
    p.PN = Pp + 3*9600; p.EdN = Edp + 3*2400; p.GqN = Gqp + 3*64;
    p.qout = qA; p.xout = xA;
    pair_kernel<true, false, false><<<dim3(NNODE), dim3(192), 0, stream>>>(p);

    // ---- P4: layer 4 -> d_out ----
    p.qcur = qA; p.xcur = xA;
    p.Cin = CA; p.Cdin = CdA; p.Adin = Ad;
    p.Ed = Edp + 3*2400; p.Gq = Gqp + 3*64; p.P = Pp + 3*9600;
    p.wm = wm[3]; p.wf = wf[3]; p.bf = bf[3];
    p.wmN = wm[3]; p.bmN = bm[3]; p.wqN = wq[3]; p.bqN = bq[3];  // unused
    p.qout = nullptr; p.xout = nullptr;
    pair_kernel<false, true, false><<<dim3(NNODE), dim3(192), 0, stream>>>(p);
}

// Round 12
// 165.170 us; speedup vs baseline: 1.4105x; 1.3050x over previous
//
#include <hip/hip_runtime.h>
#include <math.h>

#define NB 8
#define NN 150
#define NE 299          // 2*N-1
#define NNODE (NB*NN)   // 1200

struct Quat { float w, x, y, z; };

__device__ inline Quat qmul(Quat a, Quat b) {
    Quat r;
    r.w = a.w*b.w - a.x*b.x - a.y*b.y - a.z*b.z;
    r.x = a.w*b.x + a.x*b.w + a.y*b.z - a.z*b.y;
    r.y = a.w*b.y - a.x*b.z + a.y*b.w + a.z*b.x;
    r.z = a.w*b.z + a.x*b.y - a.y*b.x + a.z*b.w;
    return r;
}
__device__ inline Quat qconj(Quat a) { return Quat{a.w, -a.x, -a.y, -a.z}; }

__device__ inline float3 qrot(Quat q, float3 v) {
    float tx = 2.f*(q.y*v.z - q.z*v.y);
    float ty = 2.f*(q.z*v.x - q.x*v.z);
    float tz = 2.f*(q.x*v.y - q.y*v.x);
    float cx = q.y*tz - q.z*ty;
    float cy = q.z*tx - q.x*tz;
    float cz = q.x*ty - q.y*tx;
    float3 r;
    r.x = v.x + q.w*tx + cx;
    r.y = v.y + q.w*ty + cy;
    r.z = v.z + q.w*tz + cz;
    return r;
}

// ---------------------------------------------------------------------------
// D1: layer-1 node work (blocks 0..149, 8 nodes each) + per-layer tables:
//   150..153 : P[l][300][32] prefix sums of E rows of Wm
//   154..157 : Gq[l][9][6] = geom rows @ Wq
//   158..257 : Ed[l][299][8] = E rows @ Wq
//   258      : Csum1 = (sum_j h_j) @ WmC (factored), zero Csum2..4
// ---------------------------------------------------------------------------
struct InitArgs {
    const float* quats; const float* trans; const float* feats; const int* tptr;
    const float* wm[4]; const float* wq[4];
    const float* bm1; const float* bq1;
    float* h; float* A; float* C0; float* Ad; float* Cd0;
    float* P; float* Ed; float* Gq; float* Csum;
};

__global__ __launch_bounds__(256) void init_kernel(InitArgs a)
{
    __shared__ float sh[8][30];
    __shared__ float sA[8][32];
    __shared__ float sC[8][32];
    __shared__ float sPS[256];
    const int tid = threadIdx.x;
    const int blk = blockIdx.x;

    if (blk < 150) {
        const int nodeBase = blk*8;
        for (int idx = tid; idx < 8*30; idx += 256) {
            const int nl = idx / 30;
            const int d  = idx - nl*30;
            const int n  = nodeBase + nl;
            float v;
            if      (d < 4)  v = a.quats[n*4 + d];
            else if (d < 7)  v = a.trans[n*3 + (d-4)];
            else if (d < 29) v = a.feats[n*22 + (d-7)];
            else             v = (float)a.tptr[0] * (1.0f/1000.0f);
            sh[nl][d] = v;
            a.h[n*64 + d] = v;
        }
        __syncthreads();
        {
            const int nl = tid >> 5;
            const int k  = tid & 31;
            const int n  = nodeBase + nl;
            float av = a.bm1[k], cv = 0.f;
#pragma unroll
            for (int d = 0; d < 30; ++d) {
                const float hv = sh[nl][d];
                av = fmaf(hv, a.wm[0][d*32 + k], av);
                cv = fmaf(hv, a.wm[0][(30+d)*32 + k], cv);
            }
            a.A[n*32 + k]  = av;
            a.C0[n*32 + k] = cv;
            sA[nl][k] = av;
            sC[nl][k] = cv;
        }
        __syncthreads();
        if (tid < 96) {
            const int half = (tid >= 48) ? 1 : 0;
            const int idx  = tid - half*48;
            const int nl = idx / 6;
            const int d  = idx - nl*6;
            const float* src = half ? sC[nl] : sA[nl];
            float acc = half ? 0.f : a.bq1[d];
#pragma unroll
            for (int k = 0; k < 32; ++k) acc = fmaf(src[k], a.wq[0][k*6 + d], acc);
            (half ? a.Cd0 : a.Ad)[(nodeBase+nl)*8 + d] = acc;
        }
    } else if (blk < 154) {
        const int l = blk - 150;
        const int HDl = (l == 0) ? 30 : 64;
        const float* E = a.wm[l] + 2*HDl*32;
        float* Pl = a.P + l*9600;
        const int g = tid >> 5, k = tid & 31;    // 8 groups x 32 channels
        const int r0 = g*38;
        float part = 0.f;
        for (int r = r0; r < r0+38 && r < NE; ++r) part += E[r*32 + k];
        sPS[g*32 + k] = part;
        __syncthreads();
        float run = 0.f;
        for (int gg = 0; gg < g; ++gg) run += sPS[gg*32 + k];
        const int rw = (r0+38 < 300) ? r0+38 : 300;
        for (int r = r0; r < rw; ++r) {
            Pl[r*32 + k] = run;
            if (r < NE) run += E[r*32 + k];
        }
    } else if (blk < 158) {
        const int l = blk - 154;
        const int HDl = (l == 0) ? 30 : 64;
        const float* E  = a.wm[l] + 2*HDl*32;
        const float* Wq = a.wq[l];
        if (tid < 54) {
            const int t = tid/6, d = tid - t*6;
            float acc = 0.f;
#pragma unroll
            for (int k = 0; k < 32; ++k) acc = fmaf(E[(NE+t)*32 + k], Wq[k*6 + d], acc);
            a.Gq[l*64 + t*6 + d] = acc;
        }
    } else if (blk < 258) {
        const int bb = blk - 158;              // 0..99
        const int l = bb / 25;
        const int rbase = (bb % 25) * 12;
        const int HDl = (l == 0) ? 30 : 64;
        const float* E  = a.wm[l] + 2*HDl*32;
        const float* Wq = a.wq[l];
        if (tid < 72) {
            const int rr = tid/6, d = tid - rr*6;
            const int r = rbase + rr;
            if (r < NE) {
                float acc = 0.f;
#pragma unroll
                for (int k = 0; k < 32; ++k) acc = fmaf(E[r*32 + k], Wq[k*6 + d], acc);
                a.Ed[l*2400 + r*8 + d] = acc;
            }
        }
    } else {
        // Csum1 via factorization: Csum1[b][k] = sum_d Hsum[b][d]*WmC[d][k]
        if (tid < 240) {
            const int bb = tid/30, d = tid - bb*30;
            float acc = 0.f;
            if (d < 4)       { for (int jj=0;jj<NN;++jj) acc += a.quats[(bb*NN+jj)*4 + d]; }
            else if (d < 7)  { for (int jj=0;jj<NN;++jj) acc += a.trans[(bb*NN+jj)*3 + (d-4)]; }
            else if (d < 29) { for (int jj=0;jj<NN;++jj) acc += a.feats[(bb*NN+jj)*22 + (d-7)]; }
            else             { acc = (float)NN * ((float)a.tptr[0] * (1.0f/1000.0f)); }
            sh[bb][d] = acc;
        }
        a.Csum[256 + tid] = 0.f;     // zero layers 2..4
        a.Csum[512 + tid] = 0.f;
        a.Csum[768 + tid] = 0.f;
        __syncthreads();
        const int bb = tid >> 5, k = tid & 31;
        float acc = 0.f;
#pragma unroll
        for (int d = 0; d < 30; ++d) acc = fmaf(sh[bb][d], a.wm[0][(30+d)*32 + k], acc);
        a.Csum[bb*32 + k] = acc;
    }
}

// ---------------------------------------------------------------------------
// Thin pair kernel: one block per (b,i). Geometry + factored 6-channel delta;
// single-pass 16-row LDS-transpose reduce (no C channels -> Csum algebra);
// msum reconstructed; o; next-layer node tail (+ Csum atomicAdd).
// ---------------------------------------------------------------------------
struct PairArgs {
    const float* qcur; const float* xcur;
    const float* hbuf; const float* Abuf; const float* Cin;
    const float* Adin; const float* Cdin;
    const float* Ed; const float* Gq; const float* P; const float* Csum;
    const float* wm; const float* wf; const float* bf;
    const float* wmN; const float* bmN; const float* wqN; const float* bqN;
    float* hout; float* Aout; float* Adout; float* Cout; float* Cdout;
    float* CsumN;
    float* qout; float* xout; float* dout;
};

template<int HD, bool COMPUTE_O, bool WRITE_OUT, bool TAIL_FULL>
__global__ __launch_bounds__(192, 5) void pair_kernel(PairArgs a)
{
    constexpr int STR = 196;                  // 192 cols + pad
    constexpr int NV  = COMPUTE_O ? 16 : 7;
    __shared__ __align__(16) float sMat[NV*STR];
    __shared__ float sPr[64];
    __shared__ float sTot[16];
    __shared__ float sHi[64], sO[64], sMs[32];
    __shared__ float sGq[54], sAd[6];
    __shared__ float sA2[32], sC2[32];

    const int tid   = threadIdx.x;
    const int nodeI = blockIdx.x;
    const int b     = nodeI / NN;
    const int i     = nodeI - b*NN;
    const int j     = tid;

    // ---- staging ----
    if (COMPUTE_O) { if (tid < HD) sHi[tid] = a.hbuf[nodeI*64 + tid]; }
    if (tid < 54) sGq[tid] = a.Gq[tid];
    if (tid >= 64 && tid < 70) sAd[tid-64] = a.Adin[nodeI*8 + (tid-64)];
    __syncthreads();   // B0

    const float4 qi4 = ((const float4*)a.qcur)[nodeI];
    const Quat  qi = {qi4.x, qi4.y, qi4.z, qi4.w};
    const float3 xi = {a.xcur[nodeI*3+0], a.xcur[nodeI*3+1], a.xcur[nodeI*3+2]};

    float vals[NV];
#pragma unroll
    for (int v = 0; v < NV; ++v) vals[v] = 0.f;

    if (j < NN) {
        const int nodeJ = b*NN + j;
        const float4 q4 = ((const float4*)a.qcur)[nodeJ];
        Quat qj = {q4.x, q4.y, q4.z, q4.w};
        float3 xj = {a.xcur[nodeJ*3+0], a.xcur[nodeJ*3+1], a.xcur[nodeJ*3+2]};
        const float mm = (j == i) ? 0.f : 1.f;

        float3 diff = {xi.x - xj.x, xi.y - xj.y, xi.z - xj.z};
        Quat qjc = qconj(qj);
        float3 lx = qrot(qjc, diff);
        Quat lq = qmul(qmul(qjc, qi), qj);
        const float d2v = diff.x*diff.x + diff.y*diff.y + diff.z*diff.z;
        const float dt = fabsf(qi.w*qj.w + qi.x*qj.x + qi.y*qj.y + qi.z*qj.z);
        const float g[9] = {lx.x, lx.y, lx.z, lq.w, lq.x, lq.y, lq.z, d2v, dt};

        // delta = Ad_i + Cd_j + Ed_{i-j} + sum_t g[t]*Gq[t]   (then *mm)
        const float4* cd4 = (const float4*)(a.Cdin + nodeJ*8);
        const float4* ed4 = (const float4*)(a.Ed + (NN-1 + i - j)*8);
        const float4 c0 = cd4[0], c1 = cd4[1];
        const float4 e0 = ed4[0], e1 = ed4[1];
        float delta[6];
        delta[0] = sAd[0] + c0.x + e0.x;
        delta[1] = sAd[1] + c0.y + e0.y;
        delta[2] = sAd[2] + c0.z + e0.z;
        delta[3] = sAd[3] + c0.w + e0.w;
        delta[4] = sAd[4] + c1.x + e1.x;
        delta[5] = sAd[5] + c1.y + e1.y;
#pragma unroll
        for (int t = 0; t < 9; ++t) {
            const float gv = g[t];
#pragma unroll
            for (int d2 = 0; d2 < 6; ++d2)
                delta[d2] = fmaf(gv, sGq[t*6 + d2], delta[d2]);
        }
#pragma unroll
        for (int d2 = 0; d2 < 6; ++d2) delta[d2] *= mm;

        constexpr int vo = COMPUTE_O ? 9 : 0;
        if (COMPUTE_O) {
#pragma unroll
            for (int t = 0; t < 9; ++t) vals[t] = g[t]*mm;   // Gsum excl j==i
        }
        float3 dv = {delta[3], delta[4], delta[5]};
        float3 rd = qrot(qj, dv);
        vals[vo+0] = rd.x; vals[vo+1] = rd.y; vals[vo+2] = rd.z;
        Quat vq = {0.f, delta[0], delta[1], delta[2]};
        Quat sp = qmul(lq, vq);
        vals[vo+3] = lq.w + sp.w;
        vals[vo+4] = lq.x + sp.x;
        vals[vo+5] = lq.y + sp.y;
        vals[vo+6] = lq.z + sp.z;
    }

    // ---- single-pass LDS-transpose reduce ----
#pragma unroll
    for (int v = 0; v < NV; ++v) sMat[v*STR + tid] = vals[v];
    __syncthreads();   // B1
    if (tid < 4*NV) {
        const int ch = tid >> 2, q4i = tid & 3;
        const float4* row = (const float4*)(sMat + ch*STR + q4i*48);
        float s0 = 0.f, s1 = 0.f, s2 = 0.f, s3 = 0.f;
#pragma unroll
        for (int it = 0; it < 12; ++it) {
            const float4 r = row[it];
            s0 += r.x; s1 += r.y; s2 += r.z; s3 += r.w;
        }
        sPr[tid] = (s0+s1) + (s2+s3);
    }
    __syncthreads();   // B2
    if (tid < NV)
        sTot[tid] = (sPr[4*tid] + sPr[4*tid+1]) + (sPr[4*tid+2] + sPr[4*tid+3]);
    __syncthreads();   // B3

    if (COMPUTE_O) {
        // msum_i = 149*A_i + (Csum_b - C_i) + (P[i+150]-P[i]-E149) + Gsum.WmG
        if (tid < 32) {
            const int k = tid;
            float ms = 149.f*a.Abuf[nodeI*32 + k]
                     + a.Csum[b*32 + k] - a.Cin[nodeI*32 + k]
                     + a.P[(i+NN)*32 + k] - a.P[i*32 + k]
                     - a.wm[(2*HD + (NN-1))*32 + k];
#pragma unroll
            for (int t = 0; t < 9; ++t)
                ms = fmaf(sTot[t], a.wm[(2*HD + NE + t)*32 + k], ms);
            sMs[k] = ms;
        }
        if (tid == 64) {   // q/x epilogue (reads sTot only) in parallel
            const float inv = 1.0f / (float)(NN - 1);
            const float ux0 = ((float)NN * xi.x + sTot[9])  * inv;
            const float ux1 = ((float)NN * xi.y + sTot[10]) * inv;
            const float ux2 = ((float)NN * xi.z + sTot[11]) * inv;
            Quat s = {sTot[12], sTot[13], sTot[14], sTot[15]};
            const float nrm = sqrtf(s.w*s.w + s.x*s.x + s.y*s.y + s.z*s.z);
            const float invn = 1.0f / fmaxf(nrm, 1e-12f);
            Quat u = {s.w*invn, s.x*invn, s.y*invn, s.z*invn};
            Quat uq = qmul(qmul(qi, u), qconj(qi));
            a.qout[nodeI*4+0] = uq.w; a.qout[nodeI*4+1] = uq.x;
            a.qout[nodeI*4+2] = uq.y; a.qout[nodeI*4+3] = uq.z;
            a.xout[nodeI*3+0] = ux0;  a.xout[nodeI*3+1] = ux1;
            a.xout[nodeI*3+2] = ux2;
        }
        __syncthreads();   // B4
        if (tid < 64) {
            float acc0 = a.bf[tid], acc1 = 0.f;
#pragma unroll 8
            for (int d2 = 0; d2 < HD; d2 += 2) {
                acc0 = fmaf(sHi[d2],   a.wf[d2*64 + tid],     acc0);
                acc1 = fmaf(sHi[d2+1], a.wf[(d2+1)*64 + tid], acc1);
            }
#pragma unroll 8
            for (int k = 0; k < 32; k += 2) {
                acc0 = fmaf(sMs[k],   a.wf[(HD+k)*64 + tid],   acc0);
                acc1 = fmaf(sMs[k+1], a.wf[(HD+k+1)*64 + tid], acc1);
            }
            sO[tid] = acc0 + acc1;
        }
        __syncthreads();   // B5
        // ---- tail: next layer node work ----
        if (tid < 64) {
            const float hn = fmaxf(sO[tid], 0.f);   // relu
            sHi[tid] = hn;
            if (TAIL_FULL) a.hout[nodeI*64 + tid] = hn;
        }
        __syncthreads();   // B6
        if (tid < 64) {
            const int k   = tid & 31;
            const int off = (tid >= 32) ? 64 : 0;
            float acc = (tid < 32) ? a.bmN[k] : 0.f;
#pragma unroll
            for (int d2 = 0; d2 < 64; ++d2)
                acc = fmaf(sHi[d2], a.wmN[(off+d2)*32 + k], acc);
            if (tid < 32) {
                sA2[k] = acc;
                if (TAIL_FULL) a.Aout[nodeI*32 + k] = acc;
            } else {
                sC2[k] = acc;
                if (TAIL_FULL) {
                    a.Cout[nodeI*32 + k] = acc;
                    atomicAdd(&a.CsumN[b*32 + k], acc);
                }
            }
        }
        __syncthreads();   // B7
        if (tid < 12) {
            const int half = (tid >= 6) ? 1 : 0;
            const int d2 = tid - half*6;
            const float* src = half ? sC2 : sA2;
            float acc = half ? 0.f : a.bqN[d2];
#pragma unroll
            for (int k = 0; k < 32; ++k) acc = fmaf(src[k], a.wqN[k*6 + d2], acc);
            (half ? a.Cdout : a.Adout)[nodeI*8 + d2] = acc;
        }
    } else {
        if (tid == 0) {
            const float inv = 1.0f / (float)(NN - 1);
            const float ux0 = ((float)NN * xi.x + sTot[0]) * inv;
            const float ux1 = ((float)NN * xi.y + sTot[1]) * inv;
            const float ux2 = ((float)NN * xi.z + sTot[2]) * inv;
            Quat s = {sTot[3], sTot[4], sTot[5], sTot[6]};
            const float nrm = sqrtf(s.w*s.w + s.x*s.x + s.y*s.y + s.z*s.z);
            const float invn = 1.0f / fmaxf(nrm, 1e-12f);
            Quat u = {s.w*invn, s.x*invn, s.y*invn, s.z*invn};
            Quat uq = qmul(qmul(qi, u), qconj(qi));
            if (WRITE_OUT) {
                float* op = a.dout + nodeI*7;
                op[0] = uq.w; op[1] = uq.x; op[2] = uq.y; op[3] = uq.z;
                op[4] = ux0;  op[5] = ux1;  op[6] = ux2;
            } else {
                a.qout[nodeI*4+0] = uq.w; a.qout[nodeI*4+1] = uq.x;
                a.qout[nodeI*4+2] = uq.y; a.qout[nodeI*4+3] = uq.z;
                a.xout[nodeI*3+0] = ux0;  a.xout[nodeI*3+1] = ux1;
                a.xout[nodeI*3+2] = ux2;
            }
        }
    }
}

// ---------------------------------------------------------------------------

extern "C" void kernel_launch(void* const* d_in, const int* in_sizes, int n_in,
                              void* d_out, int out_size, void* d_ws, size_t ws_size,
                              hipStream_t stream) {
    const float* quats = (const float*)d_in[0];
    const float* trans = (const float*)d_in[1];
    const float* wm[4] = {(const float*)d_in[5],  (const float*)d_in[11],
                          (const float*)d_in[17], (const float*)d_in[23]};
    const float* bm[4] = {(const float*)d_in[6],  (const float*)d_in[12],
                          (const float*)d_in[18], (const float*)d_in[24]};
    const float* wf[4] = {(const float*)d_in[7],  (const float*)d_in[13],
                          (const float*)d_in[19], (const float*)d_in[25]};
    const float* bf[4] = {(const float*)d_in[8],  (const float*)d_in[14],
                          (const float*)d_in[20], (const float*)d_in[26]};
    const float* wq[4] = {(const float*)d_in[9],  (const float*)d_in[15],
                          (const float*)d_in[21], (const float*)d_in[27]};
    const float* bq[4] = {(const float*)d_in[10], (const float*)d_in[16],
                          (const float*)d_in[22], (const float*)d_in[28]};

    float* ws = (float*)d_ws;
    float* h   = ws;               // 1200*64
    float* A   = h   + NNODE*64;   // 1200*32
    float* CA  = A   + NNODE*32;   // 1200*32
    float* CB  = CA  + NNODE*32;   // 1200*32
    float* Ad  = CB  + NNODE*32;   // 1200*8
    float* CdA = Ad  + NNODE*8;    // 1200*8
    float* CdB = CdA + NNODE*8;    // 1200*8
    float* qA  = CdB + NNODE*8;    // 1200*4
    float* xA  = qA  + NNODE*4;    // 1200*3
    float* qB  = xA  + NNODE*3;    // 1200*4
    float* xB  = qB  + NNODE*4;    // 1200*3
    float* Pp  = xB  + NNODE*3;    // 4*300*32
    float* Edp = Pp  + 4*9600;     // 4*300*8
    float* Gqp = Edp + 4*2400;     // 4*64
    float* Cs  = Gqp + 256;        // 4*256

    // ---- D1 ----
    InitArgs ia;
    ia.quats = quats; ia.trans = trans;
    ia.feats = (const float*)d_in[2];
    ia.tptr  = (const int*)d_in[4];
    for (int l = 0; l < 4; ++l) { ia.wm[l] = wm[l]; ia.wq[l] = wq[l]; }
    ia.bm1 = bm[0]; ia.bq1 = bq[0];
    ia.h = h; ia.A = A; ia.C0 = CA; ia.Ad = Ad; ia.Cd0 = CdA;
    ia.P = Pp; ia.Ed = Edp; ia.Gq = Gqp; ia.Csum = Cs;
    init_kernel<<<dim3(259), dim3(256), 0, stream>>>(ia);

    PairArgs p;
    p.dout = (float*)d_out;

    // ---- P1: layer 1 ----
    p.qcur = quats; p.xcur = trans;
    p.hbuf = h; p.Abuf = A; p.Cin = CA; p.Adin = Ad; p.Cdin = CdA;
    p.Ed = Edp + 0*2400; p.Gq = Gqp + 0*64; p.P = Pp + 0*9600; p.Csum = Cs + 0*256;
    p.wm = wm[0]; p.wf = wf[0]; p.bf = bf[0];
    p.wmN = wm[1]; p.bmN = bm[1]; p.wqN = wq[1]; p.bqN = bq[1];
    p.hout = h; p.Aout = A; p.Adout = Ad; p.Cout = CB; p.Cdout = CdB;
    p.CsumN = Cs + 1*256;
    p.qout = qA; p.xout = xA;
    pair_kernel<30, true, false, true><<<dim3(NNODE), dim3(192), 0, stream>>>(p);

    // ---- P2: layer 2 ----
    p.qcur = qA; p.xcur = xA;
    p.Cin = CB; p.Cdin = CdB;
    p.Ed = Edp + 1*2400; p.Gq = Gqp + 1*64; p.P = Pp + 1*9600; p.Csum = Cs + 1*256;
    p.wm = wm[1]; p.wf = wf[1]; p.bf = bf[1];
    p.wmN = wm[2]; p.bmN = bm[2]; p.wqN = wq[2]; p.bqN = bq[2];
    p.Cout = CA; p.Cdout = CdA;
    p.CsumN = Cs + 2*256;
    p.qout = qB; p.xout = xB;
    pair_kernel<64, true, false, true><<<dim3(NNODE), dim3(192), 0, stream>>>(p);

    // ---- P3: layer 3 (light tail: L4 needs only Ad/Cd) ----
    p.qcur = qB; p.xcur = xB;
    p.Cin = CA; p.Cdin = CdA;
    p.Ed = Edp + 2*2400; p.Gq = Gqp + 2*64; p.P = Pp + 2*9600; p.Csum = Cs + 2*256;
    p.wm = wm[2]; p.wf = wf[2]; p.bf = bf[2];
    p.wmN = wm[3]; p.bmN = bm[3]; p.wqN = wq[3]; p.bqN = bq[3];
    p.Cout = CB; p.Cdout = CdB;
    p.CsumN = Cs + 3*256;
    p.qout = qA; p.xout = xA;
    pair_kernel<64, true, false, false><<<dim3(NNODE), dim3(192), 0, stream>>>(p);

    // ---- P4: layer 4 -> d_out ----
    p.qcur = qA; p.xcur = xA;
    p.Cin = CB; p.Cdin = CdB; p.Adin = Ad;
    p.Ed = Edp + 3*2400; p.Gq = Gqp + 3*64; p.P = Pp + 3*9600; p.Csum = Cs + 3*256;
    p.wm = wm[3]; p.wf = wf[3]; p.bf = bf[3];
    p.wmN = wm[3]; p.bmN = bm[3]; p.wqN = wq[3]; p.bqN = bq[3];  // unused
    p.qout = nullptr; p.xout = nullptr;
    pair_kernel<64, false, true, false><<<dim3(NNODE), dim3(192), 0, stream>>>(p);
}